// Round 9
// baseline (15.987 us; speedup 1.0000x reference)
//
#include <hip/hip_runtime.h>
#include <math.h>

#define BATCH 64
#define TLEN 8000
#define NCHUNK 16
#define TPC (TLEN / NCHUNK)     // 500 frames per chunk
#define NPART 21                // 16 (M) + 4 (V) + 1 (mask sum)
#define NGROUP 4                // kernel2: chunk groups
#define CPG (NCHUNK / NGROUP)   // 4 chunks per group

// fast, stable log-sigmoid: min(x,0) - log(1 + exp(-|x|))
__device__ __forceinline__ float log_sigmoid_f(float x) {
    float e = __expf(-fabsf(x));
    return fminf(x, 0.0f) - __logf(1.0f + e);
}

__global__ __launch_bounds__(256) void pit_partial(
    const float* __restrict__ logits, const float* __restrict__ targets,
    const float* __restrict__ mask, float* __restrict__ ws)
{
    const int chunk = blockIdx.x;   // 0..NCHUNK-1
    const int b     = blockIdx.y;   // 0..BATCH-1
    const int tid   = threadIdx.x;
    const int wid   = tid >> 6;
    const int lane  = tid & 63;
    const int t0    = chunk * TPC;

    float acc[NPART];
    #pragma unroll
    for (int k = 0; k < NPART; ++k) acc[k] = 0.f;

    const float4* lg4 = (const float4*)(logits  + (size_t)b * TLEN * 4);
    const float4* tg4 = (const float4*)(targets + (size_t)b * TLEN * 4);
    const float*  mk  = mask + (size_t)b * TLEN;

    for (int t = t0 + tid; t < t0 + TPC; t += 256) {
        float4 xv = lg4[t];
        float4 tv = tg4[t];
        float  m  = mk[t];
        float xs[4] = {xv.x, xv.y, xv.z, xv.w};
        float ts[4] = {tv.x, tv.y, tv.z, tv.w};
        acc[20] += m;
        #pragma unroll
        for (int i = 0; i < 4; ++i) {
            float A  = log_sigmoid_f(xs[i]);
            float Bn = A - xs[i];            // log_sigmoid(-x)
            float C  = fmaf(0.5f, A, xs[i]); // POS_W*A - Bn with POS_W=1.5
            acc[16 + i] = fmaf(m, Bn, acc[16 + i]);
            float mc = m * C;
            #pragma unroll
            for (int j = 0; j < 4; ++j)
                acc[i * 4 + j] = fmaf(mc, ts[j], acc[i * 4 + j]);
        }
    }

    // ---- wave butterfly (register-only, fixed order) ----
    #pragma unroll
    for (int k = 0; k < NPART; ++k) {
        #pragma unroll
        for (int off = 32; off > 0; off >>= 1)
            acc[k] += __shfl_xor(acc[k], off);
    }

    // ---- 4 wave-partials -> LDS -> 21 threads finish (1 barrier) ----
    __shared__ float wred[4][NPART];
    if (lane == 0) {
        #pragma unroll
        for (int k = 0; k < NPART; ++k) wred[wid][k] = acc[k];
    }
    __syncthreads();

    if (tid < NPART) {
        float s = wred[0][tid] + wred[1][tid] + wred[2][tid] + wred[3][tid];
        // ws layout: [chunk][part][batch] -> coalesced reads in pit_final
        ws[(chunk * NPART + tid) * BATCH + b] = s;
    }
}

__global__ __launch_bounds__(256) void pit_final(
    const float* __restrict__ ws, float* __restrict__ out)
{
    const int tid = threadIdx.x;
    const int g   = tid >> 6;    // chunk group 0..3
    const int b   = tid & 63;    // batch element

    __shared__ float sh[NGROUP][BATCH][NPART];   // 21504 B

    // ---- stage A: 256 threads, each sums CPG chunks for (g, b) ----
    {
        float p[NPART];
        #pragma unroll
        for (int k = 0; k < NPART; ++k) p[k] = 0.f;
        #pragma unroll
        for (int c = 0; c < CPG; ++c)
            #pragma unroll
            for (int k = 0; k < NPART; ++k)
                p[k] += ws[((g * CPG + c) * NPART + k) * BATCH + b];
        #pragma unroll
        for (int k = 0; k < NPART; ++k) sh[g][b][k] = p[k];
    }
    __syncthreads();

    // ---- stage B: wave 0, one lane per batch ----
    if (tid < 64) {
        float p[NPART];
        #pragma unroll
        for (int k = 0; k < NPART; ++k) {
            float acc = sh[0][b][k];
            #pragma unroll
            for (int gg = 1; gg < NGROUP; ++gg) acc += sh[gg][b][k];
            p[k] = acc;
        }

        const float denom = fmaxf(p[20], 1.0f);
        float cost[4][4];
        #pragma unroll
        for (int i = 0; i < 4; ++i)
            #pragma unroll
            for (int j = 0; j < 4; ++j)
                cost[i][j] = -(p[i * 4 + j] + p[16 + i]) / denom;

        constexpr int PERMS[24][4] = {
            {0,1,2,3},{0,1,3,2},{0,2,1,3},{0,2,3,1},{0,3,1,2},{0,3,2,1},
            {1,0,2,3},{1,0,3,2},{1,2,0,3},{1,2,3,0},{1,3,0,2},{1,3,2,0},
            {2,0,1,3},{2,0,3,1},{2,1,0,3},{2,1,3,0},{2,3,0,1},{2,3,1,0},
            {3,0,1,2},{3,0,2,1},{3,1,0,2},{3,1,2,0},{3,2,0,1},{3,2,1,0}};
        float best = 3.4e38f;
        #pragma unroll
        for (int pi = 0; pi < 24; ++pi) {
            float s4 = cost[0][PERMS[pi][0]] + cost[1][PERMS[pi][1]]
                     + cost[2][PERMS[pi][2]] + cost[3][PERMS[pi][3]];
            best = fminf(best, s4);
        }
        float loss = best * 0.25f;

        // fixed-order 64-lane butterfly sum, then mean
        #pragma unroll
        for (int off = 32; off > 0; off >>= 1)
            loss += __shfl_xor(loss, off);
        if (tid == 0) out[0] = loss * (1.0f / BATCH);
    }
}

extern "C" void kernel_launch(void* const* d_in, const int* in_sizes, int n_in,
                              void* d_out, int out_size, void* d_ws, size_t ws_size,
                              hipStream_t stream) {
    const float* logits  = (const float*)d_in[0];
    const float* targets = (const float*)d_in[1];
    const float* mask    = (const float*)d_in[2];
    float* out = (float*)d_out;
    float* ws  = (float*)d_ws;

    pit_partial<<<dim3(NCHUNK, BATCH), 256, 0, stream>>>(logits, targets, mask, ws);
    pit_final<<<1, 256, 0, stream>>>(ws, out);
}

// Round 10
// 12.173 us; speedup vs baseline: 1.3133x; 1.3133x over previous
//
#include <hip/hip_runtime.h>
#include <math.h>

#define BATCH 64
#define TLEN 8000
#define NCHUNK 8
#define TPC (TLEN / NCHUNK)     // 1000 frames per chunk
#define NPART 21                // 16 (M) + 4 (V) + 1 (mask sum)
#define NGROUP 4                // kernel2: chunk groups
#define CPG (NCHUNK / NGROUP)   // 2 chunks per group

// fast, stable log-sigmoid: min(x,0) - log(1 + exp(-|x|))
__device__ __forceinline__ float log_sigmoid_f(float x) {
    float e = __expf(-fabsf(x));
    return fminf(x, 0.0f) - __logf(1.0f + e);
}

__global__ __launch_bounds__(256) void pit_partial(
    const float* __restrict__ logits, const float* __restrict__ targets,
    const float* __restrict__ mask, float* __restrict__ ws)
{
    const int chunk = blockIdx.x;   // 0..NCHUNK-1
    const int b     = blockIdx.y;   // 0..BATCH-1
    const int tid   = threadIdx.x;
    const int t0    = chunk * TPC;

    float M[4][4] = {{0.f}};
    float V[4] = {0.f};
    float msum = 0.f;

    const float4* lg4 = (const float4*)(logits  + (size_t)b * TLEN * 4);
    const float4* tg4 = (const float4*)(targets + (size_t)b * TLEN * 4);
    const float*  mk  = mask + (size_t)b * TLEN;

    for (int t = t0 + tid; t < t0 + TPC; t += 256) {
        float4 xv = lg4[t];
        float4 tv = tg4[t];
        float  m  = mk[t];
        float xs[4] = {xv.x, xv.y, xv.z, xv.w};
        float ts[4] = {tv.x, tv.y, tv.z, tv.w};
        msum += m;
        #pragma unroll
        for (int i = 0; i < 4; ++i) {
            float A  = log_sigmoid_f(xs[i]);
            float Bn = A - xs[i];            // log_sigmoid(-x)
            float C  = fmaf(0.5f, A, xs[i]); // POS_W*A - Bn with POS_W=1.5
            V[i] = fmaf(m, Bn, V[i]);
            float mc = m * C;
            #pragma unroll
            for (int j = 0; j < 4; ++j)
                M[i][j] = fmaf(mc, ts[j], M[i][j]);
        }
    }

    // ---- 3-stage deterministic LDS tree reduction (2 syncthreads) ----
    __shared__ float red[256 * NPART];          // 21504 B
    __shared__ float red2[8 * NPART];
    #pragma unroll
    for (int i = 0; i < 4; ++i)
        #pragma unroll
        for (int j = 0; j < 4; ++j)
            red[tid * NPART + i * 4 + j] = M[i][j];
    #pragma unroll
    for (int i = 0; i < 4; ++i) red[tid * NPART + 16 + i] = V[i];
    red[tid * NPART + 20] = msum;
    __syncthreads();

    {   // 8 segments x 21 parts = 168 workers, each sums 32 rows
        const int seg = tid >> 5;
        const int k   = tid & 31;
        if (k < NPART) {
            float acc = 0.f;
            #pragma unroll
            for (int i = 0; i < 32; ++i)
                acc += red[(seg * 32 + i) * NPART + k];
            red2[seg * NPART + k] = acc;
        }
    }
    __syncthreads();

    if (tid < NPART) {
        float acc = 0.f;
        #pragma unroll
        for (int s = 0; s < 8; ++s)
            acc += red2[s * NPART + tid];
        // ws layout: [chunk][part][batch] -> coalesced reads in pit_final
        ws[(chunk * NPART + tid) * BATCH + b] = acc;
    }
}

__global__ __launch_bounds__(256) void pit_final(
    const float* __restrict__ ws, float* __restrict__ out)
{
    const int tid = threadIdx.x;
    const int g   = tid >> 6;    // chunk group 0..3
    const int b   = tid & 63;    // batch element

    __shared__ float sh[NGROUP][BATCH][NPART];   // 21504 B

    // ---- stage A: 256 threads, each sums CPG chunks for (g, b) ----
    {
        float p[NPART];
        #pragma unroll
        for (int k = 0; k < NPART; ++k) p[k] = 0.f;
        #pragma unroll
        for (int c = 0; c < CPG; ++c)
            #pragma unroll
            for (int k = 0; k < NPART; ++k)
                p[k] += ws[((g * CPG + c) * NPART + k) * BATCH + b];
        #pragma unroll
        for (int k = 0; k < NPART; ++k) sh[g][b][k] = p[k];
    }
    __syncthreads();

    // ---- stage B: wave 0, one lane per batch ----
    if (tid < 64) {
        float p[NPART];
        #pragma unroll
        for (int k = 0; k < NPART; ++k) {
            float acc = sh[0][b][k];
            #pragma unroll
            for (int gg = 1; gg < NGROUP; ++gg) acc += sh[gg][b][k];
            p[k] = acc;
        }

        const float denom = fmaxf(p[20], 1.0f);
        float cost[4][4];
        #pragma unroll
        for (int i = 0; i < 4; ++i)
            #pragma unroll
            for (int j = 0; j < 4; ++j)
                cost[i][j] = -(p[i * 4 + j] + p[16 + i]) / denom;

        constexpr int PERMS[24][4] = {
            {0,1,2,3},{0,1,3,2},{0,2,1,3},{0,2,3,1},{0,3,1,2},{0,3,2,1},
            {1,0,2,3},{1,0,3,2},{1,2,0,3},{1,2,3,0},{1,3,0,2},{1,3,2,0},
            {2,0,1,3},{2,0,3,1},{2,1,0,3},{2,1,3,0},{2,3,0,1},{2,3,1,0},
            {3,0,1,2},{3,0,2,1},{3,1,0,2},{3,1,2,0},{3,2,0,1},{3,2,1,0}};
        float best = 3.4e38f;
        #pragma unroll
        for (int pi = 0; pi < 24; ++pi) {
            float s4 = cost[0][PERMS[pi][0]] + cost[1][PERMS[pi][1]]
                     + cost[2][PERMS[pi][2]] + cost[3][PERMS[pi][3]];
            best = fminf(best, s4);
        }
        float loss = best * 0.25f;

        // fixed-order 64-lane butterfly sum, then mean
        #pragma unroll
        for (int off = 32; off > 0; off >>= 1)
            loss += __shfl_xor(loss, off);
        if (tid == 0) out[0] = loss * (1.0f / BATCH);
    }
}

extern "C" void kernel_launch(void* const* d_in, const int* in_sizes, int n_in,
                              void* d_out, int out_size, void* d_ws, size_t ws_size,
                              hipStream_t stream) {
    const float* logits  = (const float*)d_in[0];
    const float* targets = (const float*)d_in[1];
    const float* mask    = (const float*)d_in[2];
    float* out = (float*)d_out;
    float* ws  = (float*)d_ws;

    pit_partial<<<dim3(NCHUNK, BATCH), 256, 0, stream>>>(logits, targets, mask, ws);
    pit_final<<<1, 256, 0, stream>>>(ws, out);
}